// Round 2
// baseline (1074.711 us; speedup 1.0000x reference)
//
#include <hip/hip_runtime.h>
#include <hip/hip_bf16.h>

// Problem constants (fixed by setup_inputs)
#define BB 32
#define HDIM 32
#define N0 16384
#define C0 3
#define E0 131072
#define N1 4096
#define E1 32768
#define N2 1024
#define E2 8192
#define N3 128
#define E3 1024
#define FDIM 4096
#define LDIM 128
#define EPSBN 1e-5f

__device__ __forceinline__ float bf2f(__hip_bfloat16 h) { return __bfloat162float(h); }
__device__ __forceinline__ float bflo(unsigned u) { return __uint_as_float(u << 16); }
__device__ __forceinline__ float bfhi(unsigned u) { return __uint_as_float(u & 0xffff0000u); }

__device__ __forceinline__ float tload(const float* p, int i) { return p[i]; }
__device__ __forceinline__ float tload(const __hip_bfloat16* p, int i) { return bf2f(p[i]); }

// ---------------- dtype detector ----------------
// Inspect first 256 32-bit words of W6. If the buffer is bf16, (u>>7)&0xFF is the
// low-half bf16's exponent field, concentrated near 118-123 for N(0,1/64) weights.
// If f32, those are uniform mantissa bits (~7% in-range). Vote; flag=1 -> bf16.
__global__ void k_detect(const unsigned* __restrict__ w, int* __restrict__ flag) {
    __shared__ int s;
    int tid = threadIdx.x;
    if (tid == 0) s = 0;
    __syncthreads();
    unsigned u = w[tid];
    int e = (u >> 7) & 0xFF;
    if (e >= 0x70 && e <= 0x82) atomicAdd(&s, 1);
    __syncthreads();
    if (tid == 0) *flag = (s > 128) ? 1 : 0;
}

// ---------------- input conversion ----------------
template <typename T>
__device__ void convert_body(const T* __restrict__ x, float* __restrict__ o, int n) {
    int i = blockIdx.x * 256 + threadIdx.x;
    if (i < n) o[i] = tload(x, i);
}
__global__ void k_convert(const void* __restrict__ x, float* __restrict__ o, int n,
                          const int* __restrict__ flag) {
    if (*flag) convert_body<__hip_bfloat16>((const __hip_bfloat16*)x, o, n);
    else       convert_body<float>((const float*)x, o, n);
}

// ---------------- CSR build ----------------
__global__ void k_count(const int* __restrict__ row, int* __restrict__ deg, int E) {
    int e = blockIdx.x * 256 + threadIdx.x;
    if (e < E) atomicAdd(&deg[row[e]], 1);
}

__global__ void __launch_bounds__(1024) k_scan(const int* __restrict__ deg,
                                               int* __restrict__ off,
                                               int* __restrict__ cur, int N) {
    __shared__ int s[1024];
    __shared__ int carry;
    int tid = threadIdx.x;
    if (tid == 0) carry = 0;
    __syncthreads();
    for (int base = 0; base < N; base += 1024) {
        int i = base + tid;
        int v = (i < N) ? deg[i] : 0;
        s[tid] = v;
        __syncthreads();
        for (int o = 1; o < 1024; o <<= 1) {
            int t = (tid >= o) ? s[tid - o] : 0;
            __syncthreads();
            s[tid] += t;
            __syncthreads();
        }
        int excl = s[tid] - v;
        int c = carry;
        if (i < N) { off[i] = c + excl; cur[i] = c + excl; }
        __syncthreads();
        if (tid == 0) carry += s[1023];
        __syncthreads();
    }
    if (tid == 0) off[N] = carry;
}

__global__ void k_scatter(const int* __restrict__ row, const int* __restrict__ col,
                          const int* __restrict__ deg, int* __restrict__ cur,
                          int* __restrict__ ccol, float* __restrict__ cw, int E) {
    int e = blockIdx.x * 256 + threadIdx.x;
    if (e >= E) return;
    int r = row[e], c = col[e];
    int pos = atomicAdd(&cur[r], 1);
    int dr = deg[r], dc = deg[c];
    float w = 0.f;
    if (dr > 0 && dc > 0)
        w = -(1.0f / sqrtf((float)dr)) * (1.0f / sqrtf((float)dc));
    ccol[pos] = c;
    cw[pos] = w;
}

// ---------------- ChebConv pieces ----------------
__global__ void k_prop(const float* __restrict__ X, float* __restrict__ O,
                       const int* __restrict__ off, const int* __restrict__ ccol,
                       const float* __restrict__ cw, int N, int C, int total) {
    int idx = blockIdx.x * 256 + threadIdx.x;
    if (idx >= total) return;
    int c = idx % C;
    int t = idx / C;
    int n = t % N;
    int b = t / N;
    const float* Xb = X + (size_t)b * N * C;
    int s = off[n], e = off[n + 1];
    float acc = 0.f;
    for (int k = s; k < e; k++)
        acc += Xb[ccol[k] * C + c] * cw[k];
    O[idx] = acc;
}

template <typename T>
__device__ void combine_body(const float* __restrict__ T0, const float* __restrict__ T1,
                             const float* __restrict__ T2, const T* __restrict__ W,
                             const T* __restrict__ bias, const int* __restrict__ pool,
                             float* __restrict__ O, int N, int C, int J, int useTanh,
                             int total) {
    int idx = blockIdx.x * 256 + threadIdx.x;
    if (idx >= total) return;
    int f = idx & (HDIM - 1);
    int t = idx / HDIM;
    int j = t % J;
    int b = t / J;
    int n = pool ? pool[j] : j;
    size_t base = ((size_t)b * N + n) * C;
    const float* t0 = T0 + base;
    const float* t1 = T1 + base;
    const float* t2 = T2 + base;
    float acc = tload(bias, f);
    for (int c = 0; c < C; c++) {
        float w0 = tload(W, (0 * C + c) * HDIM + f);
        float w1 = tload(W, (1 * C + c) * HDIM + f);
        float w2 = tload(W, (2 * C + c) * HDIM + f);
        float x0 = t0[c];
        acc += x0 * w0 + t1[c] * w1 + (2.f * t2[c] - x0) * w2;
    }
    if (useTanh) acc = tanhf(acc);
    O[idx] = acc;
}
__global__ void k_combine(const float* T0, const float* T1, const float* T2,
                          const void* W, const void* bias, const int* pool,
                          float* O, int N, int C, int J, int useTanh, int total,
                          const int* __restrict__ flag) {
    if (*flag) combine_body<__hip_bfloat16>(T0, T1, T2, (const __hip_bfloat16*)W,
                                            (const __hip_bfloat16*)bias, pool, O, N, C, J,
                                            useTanh, total);
    else       combine_body<float>(T0, T1, T2, (const float*)W, (const float*)bias, pool,
                                   O, N, C, J, useTanh, total);
}

// ---------------- MLP ----------------
template <typename T>
__device__ __forceinline__ float2 ld2w(const T* p) {
    if constexpr (sizeof(T) == 2) {
        unsigned u = *(const unsigned*)p;
        float2 r; r.x = bflo(u); r.y = bfhi(u); return r;
    } else {
        return *(const float2*)p;
    }
}

// Z[32,4096] f32 @ W[4096,4096] -> H[32,4096] f32 (pre-zeroed, atomic split-K)
// grid (8, 32): x = 512-wide f tile, y = 128-deep k chunk. 256 threads, 2 f per thread.
template <typename T>
__device__ void gemm_mlp_body(const float* __restrict__ Z, const T* __restrict__ W,
                              float* __restrict__ H) {
    __shared__ float zs[32][128];
    int tid = threadIdx.x;
    int kbase = blockIdx.y * 128;
    int f0 = blockIdx.x * 512 + tid * 2;
    for (int i = tid; i < 32 * 128; i += 256) {
        int b = i >> 7, k = i & 127;
        zs[b][k] = Z[b * 4096 + kbase + k];
    }
    __syncthreads();
    float acc0[32], acc1[32];
#pragma unroll
    for (int b = 0; b < 32; b++) { acc0[b] = 0.f; acc1[b] = 0.f; }
    const T* Wp = W + (size_t)kbase * 4096 + f0;
    for (int k4 = 0; k4 < 32; k4++) {
        float2 w0 = ld2w(Wp + (k4 * 4 + 0) * 4096);
        float2 w1 = ld2w(Wp + (k4 * 4 + 1) * 4096);
        float2 w2 = ld2w(Wp + (k4 * 4 + 2) * 4096);
        float2 w3 = ld2w(Wp + (k4 * 4 + 3) * 4096);
#pragma unroll
        for (int b = 0; b < 32; b++) {
            float4 z = *(const float4*)&zs[b][k4 * 4];
            acc0[b] += z.x * w0.x; acc1[b] += z.x * w0.y;
            acc0[b] += z.y * w1.x; acc1[b] += z.y * w1.y;
            acc0[b] += z.z * w2.x; acc1[b] += z.z * w2.y;
            acc0[b] += z.w * w3.x; acc1[b] += z.w * w3.y;
        }
    }
#pragma unroll
    for (int b = 0; b < 32; b++) {
        atomicAdd(&H[b * 4096 + f0], acc0[b]);
        atomicAdd(&H[b * 4096 + f0 + 1], acc1[b]);
    }
}
__global__ void k_gemm_mlp(const float* Z, const void* W, float* H,
                           const int* __restrict__ flag) {
    if (*flag) gemm_mlp_body<__hip_bfloat16>(Z, (const __hip_bfloat16*)W, H);
    else       gemm_mlp_body<float>(Z, (const float*)W, H);
}

// Z[32,4096] @ W9[4096,128] -> Mu[32,128] (pre-zeroed, atomic split-K). grid 64, block 128.
template <typename T>
__device__ void gemm9_body(const float* __restrict__ Z, const T* __restrict__ W9,
                           float* __restrict__ Mu) {
    __shared__ float zs[32][64];
    int tid = threadIdx.x;
    int kbase = blockIdx.x * 64;
    for (int i = tid; i < 32 * 64; i += 128) {
        int b = i >> 6, k = i & 63;
        zs[b][k] = Z[b * 4096 + kbase + k];
    }
    __syncthreads();
    float acc[32];
#pragma unroll
    for (int b = 0; b < 32; b++) acc[b] = 0.f;
    for (int k = 0; k < 64; k++) {
        float w = tload(W9, (kbase + k) * 128 + tid);
#pragma unroll
        for (int b = 0; b < 32; b++) acc[b] += zs[b][k] * w;
    }
#pragma unroll
    for (int b = 0; b < 32; b++) atomicAdd(&Mu[b * 128 + tid], acc[b]);
}
__global__ void k_gemm9(const float* Z, const void* W9, float* Mu,
                        const int* __restrict__ flag) {
    if (*flag) gemm9_body<__hip_bfloat16>(Z, (const __hip_bfloat16*)W9, Mu);
    else       gemm9_body<float>(Z, (const float*)W9, Mu);
}

// BatchNorm over batch (32) + affine + relu. one thread per f. (Linear bias cancels in BN.)
template <typename T>
__device__ void bn_relu_body(const float* __restrict__ H, const T* __restrict__ g,
                             const T* __restrict__ be, float* __restrict__ O) {
    int f = blockIdx.x * 256 + threadIdx.x;
    if (f >= 4096) return;
    float v[32];
    float s = 0.f;
#pragma unroll
    for (int b = 0; b < 32; b++) { v[b] = H[b * 4096 + f]; s += v[b]; }
    float mean = s * (1.0f / 32.0f);
    float s2 = 0.f;
#pragma unroll
    for (int b = 0; b < 32; b++) { float d = v[b] - mean; s2 += d * d; }
    float inv = 1.0f / sqrtf(s2 * (1.0f / 32.0f) + EPSBN);
    float gg = tload(g, f), bb = tload(be, f);
#pragma unroll
    for (int b = 0; b < 32; b++) {
        float o = (v[b] - mean) * inv * gg + bb;
        O[b * 4096 + f] = o > 0.f ? o : 0.f;
    }
}
__global__ void k_bn_relu(const float* H, const void* g, const void* be, float* O,
                          const int* __restrict__ flag) {
    if (*flag) bn_relu_body<__hip_bfloat16>(H, (const __hip_bfloat16*)g,
                                            (const __hip_bfloat16*)be, O);
    else       bn_relu_body<float>(H, (const float*)g, (const float*)be, O);
}

// final BN (no affine); output dtype follows detected mode. one block of 128 threads.
__device__ __forceinline__ void stout(float* o, int i, float v) { o[i] = v; }
__device__ __forceinline__ void stout(__hip_bfloat16* o, int i, float v) {
    o[i] = __float2bfloat16(v);
}
template <typename OT>
__device__ void bn_final_body(const float* __restrict__ Mu, OT* __restrict__ out) {
    int f = threadIdx.x;
    float v[32];
    float s = 0.f;
#pragma unroll
    for (int b = 0; b < 32; b++) { v[b] = Mu[b * 128 + f]; s += v[b]; }
    float mean = s * (1.0f / 32.0f);
    float s2 = 0.f;
#pragma unroll
    for (int b = 0; b < 32; b++) { float d = v[b] - mean; s2 += d * d; }
    float inv = 1.0f / sqrtf(s2 * (1.0f / 32.0f) + EPSBN);
#pragma unroll
    for (int b = 0; b < 32; b++)
        stout(out, b * 128 + f, (v[b] - mean) * inv);
}
__global__ void k_bn_final(const float* Mu, void* out, const int* __restrict__ flag) {
    if (*flag) bn_final_body<__hip_bfloat16>(Mu, (__hip_bfloat16*)out);
    else       bn_final_body<float>(Mu, (float*)out);
}

// ---------------- host ----------------
static inline int nblk(int total) { return (total + 255) / 256; }

extern "C" void kernel_launch(void* const* d_in, const int* in_sizes, int n_in,
                              void* d_out, int out_size, void* d_ws, size_t ws_size,
                              hipStream_t stream) {
    const void* x = d_in[0];
    const int* e0 = (const int*)d_in[1];
    const int* e1 = (const int*)d_in[2];
    const int* e2 = (const int*)d_in[3];
    const int* e3 = (const int*)d_in[4];
    const int* l0 = (const int*)d_in[5];
    const int* l1 = (const int*)d_in[6];
    const int* l2 = (const int*)d_in[7];
    const void* Wc1 = d_in[8];
    const void* b1  = d_in[9];
    const void* Wc2 = d_in[10];
    const void* b2  = d_in[11];
    const void* Wc3 = d_in[12];
    const void* b3  = d_in[13];
    const void* Wc4 = d_in[14];
    const void* b4  = d_in[15];
    const void* Wc5 = d_in[16];
    const void* b5  = d_in[17];
    const void* W6  = d_in[18];
    const void* g6  = d_in[20];
    const void* be6 = d_in[21];
    const void* W7  = d_in[22];
    const void* g7  = d_in[24];
    const void* be7 = d_in[25];
    const void* W8  = d_in[26];
    const void* g8  = d_in[28];
    const void* be8 = d_in[29];
    const void* W9  = d_in[30];

    // workspace carve (bytes)
    char* p = (char*)d_ws;
    size_t o = 0;
    auto carve = [&](size_t bytes) {
        void* r = (void*)(p + o);
        o += (bytes + 255) & ~(size_t)255;
        return r;
    };
    int* dflag = (int*)carve(sizeof(int));
    const size_t BIG = (size_t)BB * N1 * HDIM * sizeof(float); // 16.78 MB
    float* A  = (float*)carve(BIG);
    float* Bf = (float*)carve(BIG);
    float* Cf = (float*)carve(BIG);
    float* D  = (float*)carve(BIG);
    int*   deg  = (int*)carve((N0) * sizeof(int));
    int*   offs = (int*)carve((N0 + 1) * sizeof(int));
    int*   cur  = (int*)carve((N0) * sizeof(int));
    int*   ccol = (int*)carve(E0 * sizeof(int));
    float* cw   = (float*)carve(E0 * sizeof(float));
    float* M0   = (float*)carve((size_t)BB * FDIM * sizeof(float));
    float* M1   = (float*)carve((size_t)BB * FDIM * sizeof(float));
    float* mu   = (float*)carve((size_t)BB * LDIM * sizeof(float));
    (void)ws_size;

    // dtype detect (W6 is large, scale 1/64 -> clean separation)
    k_detect<<<1, 256, 0, stream>>>((const unsigned*)W6, dflag);

    // convert input x to f32 in A
    {
        int n = BB * N0 * C0;
        k_convert<<<nblk(n), 256, 0, stream>>>(x, A, n, dflag);
    }

    struct Lvl {
        const int* edge; int E; int N; int C;
        const void* W; const void* bias;
        const int* pool; int J; int useTanh;
        const float* in; float* outp;
        bool buildCSR;
    };
    Lvl lv[5] = {
        { e0, E0, N0, C0,   Wc1, b1, l0,      N1, 0, A, D,  true  },
        { e1, E1, N1, HDIM, Wc2, b2, l1,      N2, 1, D, A,  true  },
        { e2, E2, N2, HDIM, Wc3, b3, l2,      N3, 1, A, D,  true  },
        { e3, E3, N3, HDIM, Wc4, b4, nullptr, N3, 1, D, A,  true  },
        { e3, E3, N3, HDIM, Wc5, b5, nullptr, N3, 0, A, M0, false }, // reuse e3 CSR
    };

    for (int i = 0; i < 5; i++) {
        const Lvl& L = lv[i];
        const int* row = L.edge;
        const int* col = L.edge + L.E;
        if (L.buildCSR) {
            hipMemsetAsync(deg, 0, L.N * sizeof(int), stream);
            k_count<<<nblk(L.E), 256, 0, stream>>>(row, deg, L.E);
            k_scan<<<1, 1024, 0, stream>>>(deg, offs, cur, L.N);
            k_scatter<<<nblk(L.E), 256, 0, stream>>>(row, col, deg, cur, ccol, cw, L.E);
        }
        int total = BB * L.N * L.C;
        k_prop<<<nblk(total), 256, 0, stream>>>(L.in, Bf, offs, ccol, cw, L.N, L.C, total);
        k_prop<<<nblk(total), 256, 0, stream>>>(Bf, Cf, offs, ccol, cw, L.N, L.C, total);
        int ctot = BB * L.J * HDIM;
        k_combine<<<nblk(ctot), 256, 0, stream>>>(L.in, Bf, Cf, L.W, L.bias, L.pool,
                                                  L.outp, L.N, L.C, L.J, L.useTanh, ctot,
                                                  dflag);
    }

    // MLP: M0 holds z [32,4096]
    const void* Ws[3]  = { W6, W7, W8 };
    const void* gs[3]  = { g6, g7, g8 };
    const void* bes[3] = { be6, be7, be8 };
    for (int l = 0; l < 3; l++) {
        hipMemsetAsync(M1, 0, (size_t)BB * FDIM * sizeof(float), stream);
        dim3 grid(8, 32);
        k_gemm_mlp<<<grid, 256, 0, stream>>>(M0, Ws[l], M1, dflag);
        k_bn_relu<<<16, 256, 0, stream>>>(M1, gs[l], bes[l], M0, dflag);
    }
    hipMemsetAsync(mu, 0, (size_t)BB * LDIM * sizeof(float), stream);
    k_gemm9<<<64, 128, 0, stream>>>(M0, W9, mu, dflag);
    k_bn_final<<<1, 128, 0, stream>>>(mu, d_out, dflag);
    (void)out_size; (void)n_in; (void)in_sizes;
}

// Round 4
// 739.223 us; speedup vs baseline: 1.4538x; 1.4538x over previous
//
#include <hip/hip_runtime.h>
#include <hip/hip_bf16.h>

// ---- problem constants (fixed by setup_inputs) ----
#define BB 32
#define HD 32
#define N0 16384
#define C0 3
#define E0v 131072
#define N1 4096
#define E1v 32768
#define N2 1024
#define E2v 8192
#define N3 128
#define E3v 1024
#define FDIM 4096
#define LDIM 128
#define NT (N0 + N1 + N2 + N3)     // 21632
#define ET (E0v + E1v + E2v + E3v) // 173056
#define EPSBN 1e-5f

// All tensors are float32 (verified empirically in rounds 1-3: runtime dtype
// dispatch passed only via the f32 path; bf16 interpretation NaN-cascades to zero).

// ---------------- CSR build (all 4 levels in one pass) ----------------
__global__ void k_count(const int* __restrict__ e0, const int* __restrict__ e1,
                        const int* __restrict__ e2, const int* __restrict__ e3,
                        int* __restrict__ deg) {
    int e = blockIdx.x * 256 + threadIdx.x;
    if (e >= ET) return;
    const int* p; int idx, nb;
    if (e < E0v)                     { p = e0; idx = e; nb = 0; }
    else if (e < E0v + E1v)          { p = e1; idx = e - E0v; nb = N0; }
    else if (e < E0v + E1v + E2v)    { p = e2; idx = e - E0v - E1v; nb = N0 + N1; }
    else                             { p = e3; idx = e - E0v - E1v - E2v; nb = N0 + N1 + N2; }
    atomicAdd(&deg[nb + p[idx]], 1);
}

__global__ void __launch_bounds__(1024) k_scan(const int* __restrict__ deg,
                                               int* __restrict__ offs, int* __restrict__ cur) {
    __shared__ int ss[1024];
    int t = threadIdx.x, base = t * 22;
    int loc[22]; int s = 0;
#pragma unroll
    for (int i = 0; i < 22; i++) {
        int idx = base + i;
        int v = (idx < NT) ? deg[idx] : 0;
        loc[i] = s; s += v;
    }
    ss[t] = s;
    __syncthreads();
    int run = s;
    for (int o = 1; o < 1024; o <<= 1) {
        int y = (t >= o) ? ss[t - o] : 0;
        __syncthreads();
        run += y; ss[t] = run;
        __syncthreads();
    }
    int excl = run - s;
#pragma unroll
    for (int i = 0; i < 22; i++) {
        int idx = base + i;
        if (idx < NT) { int v = excl + loc[i]; offs[idx] = v; cur[idx] = v; }
    }
    if (t == 0) offs[NT] = ET;
}

__global__ void k_scatter(const int* __restrict__ e0, const int* __restrict__ e1,
                          const int* __restrict__ e2, const int* __restrict__ e3,
                          const int* __restrict__ deg, int* __restrict__ cur,
                          int* __restrict__ ccol, float* __restrict__ cw) {
    int e = blockIdx.x * 256 + threadIdx.x;
    if (e >= ET) return;
    const int* p; int idx, nb, El;
    if (e < E0v)                  { p = e0; idx = e; nb = 0; El = E0v; }
    else if (e < E0v + E1v)       { p = e1; idx = e - E0v; nb = N0; El = E1v; }
    else if (e < E0v + E1v + E2v) { p = e2; idx = e - E0v - E1v; nb = N0 + N1; El = E2v; }
    else                          { p = e3; idx = e - E0v - E1v - E2v; nb = N0 + N1 + N2; El = E3v; }
    int r = p[idx], c = p[El + idx];
    int pos = atomicAdd(&cur[nb + r], 1);
    int dr = deg[nb + r], dc = deg[nb + c];
    float w = 0.f;
    if (dr > 0 && dc > 0)
        w = -(1.f / sqrtf((float)dr)) * (1.f / sqrtf((float)dc));
    ccol[pos] = c;  // level-local col index
    cw[pos] = w;
}

// ---------------- graph levels ----------------
// level-0 Tx1 over all nodes: thread per (b,n), 3 channels. x f32 [B][N0][3].
__global__ void k_prop0(const float* __restrict__ x, float* __restrict__ T1,
                        const int* __restrict__ offs, const int* __restrict__ ccol,
                        const float* __restrict__ cw) {
    int idx = blockIdx.x * 256 + threadIdx.x; // b*N0+n, total 524288
    int n = idx & (N0 - 1), b = idx >> 14;
    const float* xb = x + (size_t)b * N0 * 3;
    int s = offs[n], e = offs[n + 1];
    float a0 = 0, a1 = 0, a2 = 0;
    for (int k = s; k < e; k++) {
        int col = ccol[k]; float w = cw[k];
        const float* xp = xb + col * 3;
        a0 += w * xp[0]; a1 += w * xp[1]; a2 += w * xp[2];
    }
    float* o = T1 + (size_t)idx * 3;
    o[0] = a0; o[1] = a1; o[2] = a2;
}

// levels 1-4 Tx1 over all nodes (C=32). X f32 [B][N][32].
__global__ void k_propC(const float* __restrict__ X, float* __restrict__ T1,
                        const int* __restrict__ offs, const int* __restrict__ ccol,
                        const float* __restrict__ cw, int nmask, int nshift, int total) {
    int idx = blockIdx.x * 256 + threadIdx.x;
    if (idx >= total) return;
    int c = idx & 31; int r = idx >> 5; int n = r & nmask; int b = r >> nshift;
    const float* Xb = X + ((size_t)b << (nshift + 5));
    int s = offs[n], e = offs[n + 1];
    float acc = 0.f;
    for (int k = s; k < e; k++) acc += cw[k] * Xb[(ccol[k] << 5) + c];
    T1[idx] = acc;
}

// fused: Tx2-gather (at pooled nodes only) + Cheb combine (+bias, opt tanh, opt pool)
// block = 8 j x 32 f; grid = (J/8, B)
template <int C>
__global__ void k_comb(const float* __restrict__ Xin, const float* __restrict__ T1,
                       const int* __restrict__ offs, const int* __restrict__ ccol,
                       const float* __restrict__ cw, const int* __restrict__ pool,
                       const float* __restrict__ W, const float* __restrict__ bias,
                       float* __restrict__ out, int N, int J, int doTanh) {
    __shared__ float st0[8][32], st1[8][32], st2[8][32];
    int t = threadIdx.x; int jp = t >> 5; int c = t & 31;
    int b = blockIdx.y; int j = blockIdx.x * 8 + jp;
    int n = pool ? pool[j] : j;
    if (c < C) {
        size_t xi = ((size_t)b * N + n) * C + c;
        st0[jp][c] = Xin[xi];
        st1[jp][c] = T1[xi];
        const float* Tb = T1 + (size_t)b * N * C;
        int s = offs[n], e = offs[n + 1];
        float acc = 0.f;
        for (int k = s; k < e; k++) acc += cw[k] * Tb[ccol[k] * C + c];
        st2[jp][c] = acc;
    }
    __syncthreads();
    int f = c;
    float acc = bias[f];
#pragma unroll
    for (int cc = 0; cc < C; cc++) {
        float w0 = W[(0 * C + cc) * HD + f];
        float w1 = W[(1 * C + cc) * HD + f];
        float w2 = W[(2 * C + cc) * HD + f];
        float x0 = st0[jp][cc], x1 = st1[jp][cc];
        float x2 = 2.f * st2[jp][cc] - x0;
        acc += x0 * w0 + x1 * w1 + x2 * w2;
    }
    if (doTanh) acc = tanhf(acc);
    out[((size_t)b * J + j) * HD + f] = acc;
}

// ---------------- MLP ----------------
// Z[32][4096] f32 @ W[4096][4096] f32 -> partials Hp[kc][32][4096] f32.
// grid (8, 32), block 256. thread owns f0 = bx*256+t and f0+2048. No atomics, no spill.
__global__ void __launch_bounds__(256, 1) k_gemm(const float* __restrict__ Z,
                                                 const float* __restrict__ W,
                                                 float* __restrict__ Hp) {
    int t = threadIdx.x; int bx = blockIdx.x; int kc = blockIdx.y; int kb = kc * 128;
    __shared__ float zs[32][128];
    for (int i = t; i < 1024; i += 256) {
        int fl = i * 4; int b = fl >> 7; int k = fl & 127;
        *(float4*)&zs[b][k] = *(const float4*)&Z[(size_t)b * 4096 + kb + k];
    }
    __syncthreads();
    int f0 = bx * 256 + t;
    const float* Wp = W + (size_t)kb * 4096 + f0;
    float acc0[32], acc1[32];
#pragma unroll
    for (int b = 0; b < 32; b++) { acc0[b] = 0.f; acc1[b] = 0.f; }
    for (int k4 = 0; k4 < 32; k4++) {
        float w0[4], w1[4];
#pragma unroll
        for (int j = 0; j < 4; j++) {
            w0[j] = Wp[(size_t)(k4 * 4 + j) * 4096];
            w1[j] = Wp[(size_t)(k4 * 4 + j) * 4096 + 2048];
        }
#pragma unroll
        for (int b = 0; b < 32; b++) {
            float4 z = *(const float4*)&zs[b][k4 * 4];
            acc0[b] += z.x * w0[0] + z.y * w0[1] + z.z * w0[2] + z.w * w0[3];
            acc1[b] += z.x * w1[0] + z.y * w1[1] + z.z * w1[2] + z.w * w1[3];
        }
    }
    float* o = Hp + (size_t)kc * 32 * 4096;
#pragma unroll
    for (int b = 0; b < 32; b++) {
        o[b * 4096 + f0] = acc0[b];
        o[b * 4096 + f0 + 2048] = acc1[b];
    }
}

// reduce 32 partials + BatchNorm(batch stats) + affine + relu -> Z f32
// grid 64, block 256 = 64 f x 4 bq(8 b each)
__global__ void k_bnrelu(const float* __restrict__ Hp, const float* __restrict__ g,
                         const float* __restrict__ be, float* __restrict__ Zo) {
    __shared__ float sA[4][64], sB[4][64], sm[64], si[64];
    int t = threadIdx.x; int fq = t & 63; int bq = t >> 6;
    int f = blockIdx.x * 64 + fq;
    float v[8];
#pragma unroll
    for (int i = 0; i < 8; i++) v[i] = 0.f;
    for (int p = 0; p < 32; p++) {
        const float* hp = Hp + (size_t)p * 32 * 4096;
#pragma unroll
        for (int i = 0; i < 8; i++) v[i] += hp[(bq * 8 + i) * 4096 + f];
    }
    float a = 0.f, q = 0.f;
#pragma unroll
    for (int i = 0; i < 8; i++) { a += v[i]; q += v[i] * v[i]; }
    sA[bq][fq] = a; sB[bq][fq] = q;
    __syncthreads();
    if (t < 64) {
        float m = (sA[0][t] + sA[1][t] + sA[2][t] + sA[3][t]) * (1.f / 32.f);
        float vv = (sB[0][t] + sB[1][t] + sB[2][t] + sB[3][t]) * (1.f / 32.f) - m * m;
        sm[t] = m; si[t] = rsqrtf(fmaxf(vv, 0.f) + EPSBN);
    }
    __syncthreads();
    float m = sm[fq], inv = si[fq], gg = g[f], bb = be[f];
#pragma unroll
    for (int i = 0; i < 8; i++) {
        float o = (v[i] - m) * inv * gg + bb;
        Zo[(size_t)(bq * 8 + i) * 4096 + f] = fmaxf(o, 0.f);
    }
}

// Z[32][4096] @ W9[4096][128] -> partials Mp[kc][32][128]. grid 32, block 128.
__global__ void __launch_bounds__(128, 1) k_gemm9(const float* __restrict__ Z,
                                                  const float* __restrict__ W9,
                                                  float* __restrict__ Mp) {
    int t = threadIdx.x; int kc = blockIdx.x; int kb = kc * 128;
    __shared__ float zs[32][128];
    for (int i = t; i < 1024; i += 128) {
        int fl = i * 4; int b = fl >> 7; int k = fl & 127;
        *(float4*)&zs[b][k] = *(const float4*)&Z[(size_t)b * 4096 + kb + k];
    }
    __syncthreads();
    const float* Wp = W9 + (size_t)kb * 128 + t;
    float acc[32];
#pragma unroll
    for (int b = 0; b < 32; b++) acc[b] = 0.f;
    for (int k4 = 0; k4 < 32; k4++) {
        float w[4];
#pragma unroll
        for (int j = 0; j < 4; j++) w[j] = Wp[(k4 * 4 + j) * 128];
#pragma unroll
        for (int b = 0; b < 32; b++) {
            float4 z = *(const float4*)&zs[b][k4 * 4];
            acc[b] += z.x * w[0] + z.y * w[1] + z.z * w[2] + z.w * w[3];
        }
    }
    float* o = Mp + (size_t)kc * 32 * 128;
#pragma unroll
    for (int b = 0; b < 32; b++) o[b * 128 + t] = acc[b];
}

__global__ void k_red9(const float* __restrict__ Mp, float* __restrict__ Mu) {
    int idx = blockIdx.x * 256 + threadIdx.x;
    if (idx >= 4096) return;
    float a = 0.f;
    for (int p = 0; p < 32; p++) a += Mp[(size_t)p * 4096 + idx];
    Mu[idx] = a;
}

// final BN (affine=False), f32 out. 1 block x 128.
__global__ void k_bnfinal(const float* __restrict__ Mu, float* __restrict__ out) {
    int f = threadIdx.x;
    float v[32], s = 0.f;
#pragma unroll
    for (int b = 0; b < 32; b++) { v[b] = Mu[b * 128 + f]; s += v[b]; }
    float m = s * (1.f / 32.f), q = 0.f;
#pragma unroll
    for (int b = 0; b < 32; b++) { float d = v[b] - m; q += d * d; }
    float inv = rsqrtf(q * (1.f / 32.f) + EPSBN);
#pragma unroll
    for (int b = 0; b < 32; b++) out[b * 128 + f] = (v[b] - m) * inv;
}

// ---------------- host ----------------
extern "C" void kernel_launch(void* const* d_in, const int* in_sizes, int n_in,
                              void* d_out, int out_size, void* d_ws, size_t ws_size,
                              hipStream_t stream) {
    const float* x  = (const float*)d_in[0];
    const int* e0 = (const int*)d_in[1];
    const int* e1 = (const int*)d_in[2];
    const int* e2 = (const int*)d_in[3];
    const int* e3 = (const int*)d_in[4];
    const int* l0 = (const int*)d_in[5];
    const int* l1 = (const int*)d_in[6];
    const int* l2 = (const int*)d_in[7];
    const float* Wc1 = (const float*)d_in[8];
    const float* b1  = (const float*)d_in[9];
    const float* Wc2 = (const float*)d_in[10];
    const float* b2  = (const float*)d_in[11];
    const float* Wc3 = (const float*)d_in[12];
    const float* b3  = (const float*)d_in[13];
    const float* Wc4 = (const float*)d_in[14];
    const float* b4  = (const float*)d_in[15];
    const float* Wc5 = (const float*)d_in[16];
    const float* b5  = (const float*)d_in[17];
    const float* W6  = (const float*)d_in[18];
    const float* g6  = (const float*)d_in[20];
    const float* be6 = (const float*)d_in[21];
    const float* W7  = (const float*)d_in[22];
    const float* g7  = (const float*)d_in[24];
    const float* be7 = (const float*)d_in[25];
    const float* W8  = (const float*)d_in[26];
    const float* g8  = (const float*)d_in[28];
    const float* be8 = (const float*)d_in[29];
    const float* W9  = (const float*)d_in[30];
    float* out = (float*)d_out;

    char* p = (char*)d_ws;
    size_t o = 0;
    auto carve = [&](size_t bytes) {
        void* r = (void*)(p + o);
        o += (bytes + 255) & ~(size_t)255;
        return r;
    };
    float* Tbuf = (float*)carve((size_t)BB * N1 * HD * sizeof(float)); // 16.8 MB (max T1)
    float* Abuf = (float*)carve((size_t)BB * N1 * HD * sizeof(float)); // Y1 / Y3
    float* Bbuf = (float*)carve((size_t)BB * N2 * HD * sizeof(float)); // Y2 / Y4
    float* Hp   = (float*)carve((size_t)32 * BB * FDIM * sizeof(float)); // 16 MB
    float* Zb0  = (float*)carve((size_t)BB * FDIM * sizeof(float));
    float* Zb1  = (float*)carve((size_t)BB * FDIM * sizeof(float));
    float* Mp   = (float*)carve((size_t)32 * BB * LDIM * sizeof(float));
    float* Mu   = (float*)carve((size_t)BB * LDIM * sizeof(float));
    int* deg  = (int*)carve(NT * sizeof(int));
    int* offs = (int*)carve((NT + 1) * sizeof(int));
    int* cur  = (int*)carve(NT * sizeof(int));
    int* ccol = (int*)carve(ET * sizeof(int));
    float* cw = (float*)carve(ET * sizeof(float));
    (void)ws_size;

    // --- CSR for all 4 levels in one pass ---
    hipMemsetAsync(deg, 0, NT * sizeof(int), stream);
    k_count<<<(ET + 255) / 256, 256, 0, stream>>>(e0, e1, e2, e3, deg);
    k_scan<<<1, 1024, 0, stream>>>(deg, offs, cur);
    k_scatter<<<(ET + 255) / 256, 256, 0, stream>>>(e0, e1, e2, e3, deg, cur, ccol, cw);

    const int* off0 = offs;
    const int* off1 = offs + N0;
    const int* off2 = offs + N0 + N1;
    const int* off3 = offs + N0 + N1 + N2;

    // --- level 0: Tx1 everywhere, fused Tx2+combine at pooled nodes ---
    k_prop0<<<(BB * N0) / 256, 256, 0, stream>>>(x, Tbuf, off0, ccol, cw);
    k_comb<3><<<dim3(N1 / 8, BB), 256, 0, stream>>>(x, Tbuf, off0, ccol, cw, l0,
                                                    Wc1, b1, Abuf, N0, N1, 0);
    // --- level 1 ---
    k_propC<<<(BB * N1 * HD) / 256, 256, 0, stream>>>(Abuf, Tbuf, off1, ccol, cw,
                                                      N1 - 1, 12, BB * N1 * HD);
    k_comb<32><<<dim3(N2 / 8, BB), 256, 0, stream>>>(Abuf, Tbuf, off1, ccol, cw, l1,
                                                     Wc2, b2, Bbuf, N1, N2, 1);
    // --- level 2 ---
    k_propC<<<(BB * N2 * HD) / 256, 256, 0, stream>>>(Bbuf, Tbuf, off2, ccol, cw,
                                                      N2 - 1, 10, BB * N2 * HD);
    k_comb<32><<<dim3(N3 / 8, BB), 256, 0, stream>>>(Bbuf, Tbuf, off2, ccol, cw, l2,
                                                     Wc3, b3, Abuf, N2, N3, 1);
    // --- level 3 (no pool) ---
    k_propC<<<(BB * N3 * HD) / 256, 256, 0, stream>>>(Abuf, Tbuf, off3, ccol, cw,
                                                      N3 - 1, 7, BB * N3 * HD);
    k_comb<32><<<dim3(N3 / 8, BB), 256, 0, stream>>>(Abuf, Tbuf, off3, ccol, cw,
                                                     nullptr, Wc4, b4, Bbuf, N3, N3, 1);
    // --- level 4 (no pool, no tanh) -> Z0 [32][4096] ---
    k_propC<<<(BB * N3 * HD) / 256, 256, 0, stream>>>(Bbuf, Tbuf, off3, ccol, cw,
                                                      N3 - 1, 7, BB * N3 * HD);
    k_comb<32><<<dim3(N3 / 8, BB), 256, 0, stream>>>(Bbuf, Tbuf, off3, ccol, cw,
                                                     nullptr, Wc5, b5, Zb0, N3, N3, 0);

    // --- MLP: 3 x (GEMM split-K + BN/ReLU) ---
    const float* Ws[3]  = { W6, W7, W8 };
    const float* gs[3]  = { g6, g7, g8 };
    const float* bes[3] = { be6, be7, be8 };
    float* zin = Zb0; float* zout = Zb1;
    for (int l = 0; l < 3; l++) {
        k_gemm<<<dim3(8, 32), 256, 0, stream>>>(zin, Ws[l], Hp);
        k_bnrelu<<<64, 256, 0, stream>>>(Hp, gs[l], bes[l], zout);
        float* tmp = zin; zin = zout; zout = tmp;
    }
    // --- final linear + BN ---
    k_gemm9<<<32, 128, 0, stream>>>(zin, W9, Mp);
    k_red9<<<16, 256, 0, stream>>>(Mp, Mu);
    k_bnfinal<<<1, 128, 0, stream>>>(Mu, out);
    (void)out_size; (void)n_in; (void)in_sizes;
}

// Round 5
// 611.673 us; speedup vs baseline: 1.7570x; 1.2085x over previous
//
#include <hip/hip_runtime.h>
#include <hip/hip_bf16.h>

// ---- problem constants (fixed by setup_inputs) ----
#define BB 32
#define HD 32
#define N0 16384
#define C0 3
#define E0v 131072
#define N1 4096
#define E1v 32768
#define N2 1024
#define E2v 8192
#define N3 128
#define E3v 1024
#define FDIM 4096
#define LDIM 128
#define NT (N0 + N1 + N2 + N3)     // 21632
#define ET (E0v + E1v + E2v + E3v) // 173056
#define EPSBN 1e-5f
// All tensors are float32 (established round 4).

// ---------------- CSR build (all 4 levels in one pass) ----------------
__global__ void k_count(const int* __restrict__ e0, const int* __restrict__ e1,
                        const int* __restrict__ e2, const int* __restrict__ e3,
                        int* __restrict__ deg) {
    int e = blockIdx.x * 256 + threadIdx.x;
    if (e >= ET) return;
    const int* p; int idx, nb;
    if (e < E0v)                     { p = e0; idx = e; nb = 0; }
    else if (e < E0v + E1v)          { p = e1; idx = e - E0v; nb = N0; }
    else if (e < E0v + E1v + E2v)    { p = e2; idx = e - E0v - E1v; nb = N0 + N1; }
    else                             { p = e3; idx = e - E0v - E1v - E2v; nb = N0 + N1 + N2; }
    atomicAdd(&deg[nb + p[idx]], 1);
}

__global__ void __launch_bounds__(1024) k_scan(const int* __restrict__ deg,
                                               int* __restrict__ offs, int* __restrict__ cur) {
    __shared__ int ss[1024];
    int t = threadIdx.x, base = t * 22;
    int loc[22]; int s = 0;
#pragma unroll
    for (int i = 0; i < 22; i++) {
        int idx = base + i;
        int v = (idx < NT) ? deg[idx] : 0;
        loc[i] = s; s += v;
    }
    ss[t] = s;
    __syncthreads();
    int run = s;
    for (int o = 1; o < 1024; o <<= 1) {
        int y = (t >= o) ? ss[t - o] : 0;
        __syncthreads();
        run += y; ss[t] = run;
        __syncthreads();
    }
    int excl = run - s;
#pragma unroll
    for (int i = 0; i < 22; i++) {
        int idx = base + i;
        if (idx < NT) { int v = excl + loc[i]; offs[idx] = v; cur[idx] = v; }
    }
    if (t == 0) offs[NT] = ET;
}

__global__ void k_scatter(const int* __restrict__ e0, const int* __restrict__ e1,
                          const int* __restrict__ e2, const int* __restrict__ e3,
                          const int* __restrict__ deg, int* __restrict__ cur,
                          int* __restrict__ ccol, float* __restrict__ cw) {
    int e = blockIdx.x * 256 + threadIdx.x;
    if (e >= ET) return;
    const int* p; int idx, nb, El;
    if (e < E0v)                  { p = e0; idx = e; nb = 0; El = E0v; }
    else if (e < E0v + E1v)       { p = e1; idx = e - E0v; nb = N0; El = E1v; }
    else if (e < E0v + E1v + E2v) { p = e2; idx = e - E0v - E1v; nb = N0 + N1; El = E2v; }
    else                          { p = e3; idx = e - E0v - E1v - E2v; nb = N0 + N1 + N2; El = E3v; }
    int r = p[idx], c = p[El + idx];
    int pos = atomicAdd(&cur[nb + r], 1);
    int dr = deg[nb + r], dc = deg[nb + c];
    float w = 0.f;
    if (dr > 0 && dc > 0)
        w = -(1.f / sqrtf((float)dr)) * (1.f / sqrtf((float)dc));
    ccol[pos] = c;  // level-local col index
    cw[pos] = w;
}

// ---------------- transpose x [B][N0][3] -> xt [N0][96] (q = b*3+c) ----------------
__global__ void k_transpose(const float* __restrict__ x, float* __restrict__ xt) {
    __shared__ float t0[32][33], t1[32][33], t2[32][33];
    int tx = threadIdx.x, ty = threadIdx.y;      // (32, 8)
    int n0 = blockIdx.x * 32;
#pragma unroll
    for (int i = 0; i < 4; i++) {
        int b = ty * 4 + i;
        size_t base = ((size_t)b * N0 + n0 + tx) * 3;
        t0[tx][b] = x[base];
        t1[tx][b] = x[base + 1];
        t2[tx][b] = x[base + 2];
    }
    __syncthreads();
#pragma unroll
    for (int i = 0; i < 4; i++) {
        int nl = ty * 4 + i;
        size_t o = (size_t)(n0 + nl) * 96 + tx * 3;
        xt[o]     = t0[nl][tx];
        xt[o + 1] = t1[nl][tx];
        xt[o + 2] = t2[nl][tx];
    }
}

// ---------------- level-0 prop: T1t[n][q] = sum_edges w * xt[col][q] ----------------
__global__ void k_prop0(const float* __restrict__ xt, float* __restrict__ T1t,
                        const int* __restrict__ offs, const int* __restrict__ ccol,
                        const float* __restrict__ cw) {
    int idx = blockIdx.x * 256 + threadIdx.x;  // total N0*96
    int n = (unsigned)idx / 96u;
    int q = idx - n * 96;
    int s = offs[n], e = offs[n + 1];
    float acc = 0.f;
    for (int k = s; k < e; k++)
        acc += cw[k] * xt[(size_t)ccol[k] * 96 + q];
    T1t[idx] = acc;
}

// ---------------- level-0 combine: block=64, one j per block ----------------
// out Y1[j][b*32+f] = bias[f] + sum_c x0*W0 + x1*W1 + (2*T2-x0)*W2   (no tanh)
__global__ void k_comb0(const float* __restrict__ xt, const float* __restrict__ T1t,
                        const int* __restrict__ offs, const int* __restrict__ ccol,
                        const float* __restrict__ cw, const int* __restrict__ pool,
                        const float* __restrict__ W, const float* __restrict__ bias,
                        float* __restrict__ Yout) {
    __shared__ float s0[96], s1[96], s2[96], sw[288], sb[32];
    int t = threadIdx.x;
    int j = blockIdx.x;
    int n = pool[j];
    size_t nb = (size_t)n * 96;
    // load x0, x1
    s0[t] = xt[nb + t];
    s1[t] = T1t[nb + t];
    if (t < 32) { s0[64 + t] = xt[nb + 64 + t]; s1[64 + t] = T1t[nb + 64 + t]; }
    // gather T2 = prop(T1) at this node
    {
        int s = offs[n], e = offs[n + 1];
        float a0 = 0.f, a1 = 0.f;
        for (int k = s; k < e; k++) {
            const float* bp = T1t + (size_t)ccol[k] * 96;
            float w = cw[k];
            a0 += w * bp[t];
            if (t < 32) a1 += w * bp[64 + t];
        }
        s2[t] = a0;
        if (t < 32) s2[64 + t] = a1;
    }
    for (int i = t; i < 288; i += 64) sw[i] = W[i];
    if (t < 32) sb[t] = bias[t];
    __syncthreads();

    int f0 = (t & 7) * 4;
    int b0 = (t >> 3) * 4;
    float acc[4][4];
#pragma unroll
    for (int bi = 0; bi < 4; bi++)
#pragma unroll
        for (int fi = 0; fi < 4; fi++) acc[bi][fi] = sb[f0 + fi];
#pragma unroll
    for (int c = 0; c < 3; c++) {
        float4 w0 = *(float4*)&sw[(0 * 3 + c) * 32 + f0];
        float4 w1 = *(float4*)&sw[(1 * 3 + c) * 32 + f0];
        float4 w2 = *(float4*)&sw[(2 * 3 + c) * 32 + f0];
#pragma unroll
        for (int bi = 0; bi < 4; bi++) {
            int b = b0 + bi;
            float x0 = s0[b * 3 + c], x1 = s1[b * 3 + c];
            float x2 = 2.f * s2[b * 3 + c] - x0;
            acc[bi][0] += x0 * w0.x + x1 * w1.x + x2 * w2.x;
            acc[bi][1] += x0 * w0.y + x1 * w1.y + x2 * w2.y;
            acc[bi][2] += x0 * w0.z + x1 * w1.z + x2 * w2.z;
            acc[bi][3] += x0 * w0.w + x1 * w1.w + x2 * w2.w;
        }
    }
#pragma unroll
    for (int bi = 0; bi < 4; bi++) {
        float4 v = { acc[bi][0], acc[bi][1], acc[bi][2], acc[bi][3] };
        *(float4*)&Yout[(size_t)j * 1024 + (b0 + bi) * 32 + f0] = v;
    }
}

// ---------------- levels 1-4 prop: T1[n][q] = sum w * Y[col][q], q in [0,1024) ----------------
__global__ void k_propC(const float* __restrict__ Yin, float* __restrict__ T1,
                        const int* __restrict__ offs, const int* __restrict__ ccol,
                        const float* __restrict__ cw) {
    int idx = blockIdx.x * 256 + threadIdx.x;
    int n = idx >> 10;
    int q = idx & 1023;
    int s = offs[n], e = offs[n + 1];
    float acc = 0.f;
    for (int k = s; k < e; k++)
        acc += cw[k] * Yin[((size_t)ccol[k] << 10) + q];
    T1[idx] = acc;
}

// ---------------- levels 1-4 combine: block=64, one j per block ----------------
// Y layout node-major [J][b*32+f]; optional tanh; optional batch-major output (level 4).
__global__ void k_combC(const float* __restrict__ Yin, const float* __restrict__ T1,
                        const int* __restrict__ offs, const int* __restrict__ ccol,
                        const float* __restrict__ cw, const int* __restrict__ pool,
                        const float* __restrict__ W, const float* __restrict__ bias,
                        float* __restrict__ Yout, int doTanh, int bMajor) {
    __shared__ float s0[32 * 33], s1[32 * 33], s2[32 * 33], sw[3072], sb[32];
    int t = threadIdx.x;
    int j = blockIdx.x;
    int n = pool ? pool[j] : j;
    size_t nb = (size_t)n << 10;
#pragma unroll
    for (int i = 0; i < 16; i++) {
        int q = t + i * 64;
        int li = (q >> 5) * 33 + (q & 31);
        s0[li] = Yin[nb + q];
        s1[li] = T1[nb + q];
    }
    {
        int s = offs[n], e = offs[n + 1];
        float ga[16];
#pragma unroll
        for (int i = 0; i < 16; i++) ga[i] = 0.f;
        for (int k = s; k < e; k++) {
            const float* bp = T1 + ((size_t)ccol[k] << 10);
            float w = cw[k];
#pragma unroll
            for (int i = 0; i < 16; i++) ga[i] += w * bp[t + i * 64];
        }
#pragma unroll
        for (int i = 0; i < 16; i++) {
            int q = t + i * 64;
            s2[(q >> 5) * 33 + (q & 31)] = ga[i];
        }
    }
    for (int i = t; i < 768; i += 64) ((float4*)sw)[i] = ((const float4*)W)[i];
    if (t < 32) sb[t] = bias[t];
    __syncthreads();

    int f0 = (t & 7) * 4;
    int b0 = (t >> 3) * 4;
    float acc[4][4];
#pragma unroll
    for (int bi = 0; bi < 4; bi++)
#pragma unroll
        for (int fi = 0; fi < 4; fi++) acc[bi][fi] = sb[f0 + fi];
    for (int c = 0; c < 32; c++) {
        float4 w0 = *(float4*)&sw[c * 32 + f0];
        float4 w1 = *(float4*)&sw[1024 + c * 32 + f0];
        float4 w2 = *(float4*)&sw[2048 + c * 32 + f0];
#pragma unroll
        for (int bi = 0; bi < 4; bi++) {
            int li = (b0 + bi) * 33 + c;
            float x0 = s0[li], x1 = s1[li];
            float x2 = 2.f * s2[li] - x0;
            acc[bi][0] += x0 * w0.x + x1 * w1.x + x2 * w2.x;
            acc[bi][1] += x0 * w0.y + x1 * w1.y + x2 * w2.y;
            acc[bi][2] += x0 * w0.z + x1 * w1.z + x2 * w2.z;
            acc[bi][3] += x0 * w0.w + x1 * w1.w + x2 * w2.w;
        }
    }
    if (doTanh) {
#pragma unroll
        for (int bi = 0; bi < 4; bi++)
#pragma unroll
            for (int fi = 0; fi < 4; fi++) acc[bi][fi] = tanhf(acc[bi][fi]);
    }
#pragma unroll
    for (int bi = 0; bi < 4; bi++) {
        float4 v = { acc[bi][0], acc[bi][1], acc[bi][2], acc[bi][3] };
        if (bMajor)
            *(float4*)&Yout[(size_t)(b0 + bi) * FDIM + j * 32 + f0] = v;
        else
            *(float4*)&Yout[((size_t)j << 10) + (b0 + bi) * 32 + f0] = v;
    }
}

// ---------------- MLP ----------------
// Z[32][4096] @ W[4096][4096] -> Hp[kc][32][4096] partials. grid (16,32), block 256.
__global__ void __launch_bounds__(256) k_gemm(const float* __restrict__ Z,
                                              const float* __restrict__ W,
                                              float* __restrict__ Hp) {
    int t = threadIdx.x; int bx = blockIdx.x; int kc = blockIdx.y; int kb = kc * 128;
    __shared__ float zs[32][128];
    for (int i = t; i < 1024; i += 256) {
        int fl = i * 4; int b = fl >> 7; int k = fl & 127;
        *(float4*)&zs[b][k] = *(const float4*)&Z[(size_t)b * 4096 + kb + k];
    }
    __syncthreads();
    int f0 = bx * 256 + t;
    const float* Wp = W + (size_t)kb * 4096 + f0;
    float acc[32];
#pragma unroll
    for (int b = 0; b < 32; b++) acc[b] = 0.f;
    for (int k4 = 0; k4 < 32; k4++) {
        float w[4];
#pragma unroll
        for (int j = 0; j < 4; j++) w[j] = Wp[(size_t)(k4 * 4 + j) * 4096];
#pragma unroll
        for (int b = 0; b < 32; b++) {
            float4 z = *(const float4*)&zs[b][k4 * 4];
            acc[b] += z.x * w[0] + z.y * w[1] + z.z * w[2] + z.w * w[3];
        }
    }
    float* o = Hp + (size_t)kc * 32 * 4096;
#pragma unroll
    for (int b = 0; b < 32; b++) o[b * 4096 + f0] = acc[b];
}

// reduce 32 partials + BN(batch) + affine + relu. grid 64, block 256.
__global__ void k_bnrelu(const float* __restrict__ Hp, const float* __restrict__ g,
                         const float* __restrict__ be, float* __restrict__ Zo) {
    __shared__ float sA[4][64], sB[4][64], sm[64], si[64];
    int t = threadIdx.x; int fq = t & 63; int bq = t >> 6;
    int f = blockIdx.x * 64 + fq;
    float v[8];
#pragma unroll
    for (int i = 0; i < 8; i++) v[i] = 0.f;
    for (int p = 0; p < 32; p++) {
        const float* hp = Hp + (size_t)p * 32 * 4096;
#pragma unroll
        for (int i = 0; i < 8; i++) v[i] += hp[(bq * 8 + i) * 4096 + f];
    }
    float a = 0.f, q = 0.f;
#pragma unroll
    for (int i = 0; i < 8; i++) { a += v[i]; q += v[i] * v[i]; }
    sA[bq][fq] = a; sB[bq][fq] = q;
    __syncthreads();
    if (t < 64) {
        float m = (sA[0][t] + sA[1][t] + sA[2][t] + sA[3][t]) * (1.f / 32.f);
        float vv = (sB[0][t] + sB[1][t] + sB[2][t] + sB[3][t]) * (1.f / 32.f) - m * m;
        sm[t] = m; si[t] = rsqrtf(fmaxf(vv, 0.f) + EPSBN);
    }
    __syncthreads();
    float m = sm[fq], inv = si[fq], gg = g[f], bb = be[f];
#pragma unroll
    for (int i = 0; i < 8; i++) {
        float o = (v[i] - m) * inv * gg + bb;
        Zo[(size_t)(bq * 8 + i) * 4096 + f] = fmaxf(o, 0.f);
    }
}

// Z[32][4096] @ W9[4096][128] -> Mp[kc][32][128]. grid 32, block 128.
__global__ void __launch_bounds__(128) k_gemm9(const float* __restrict__ Z,
                                               const float* __restrict__ W9,
                                               float* __restrict__ Mp) {
    int t = threadIdx.x; int kc = blockIdx.x; int kb = kc * 128;
    __shared__ float zs[32][128];
    for (int i = t; i < 1024; i += 128) {
        int fl = i * 4; int b = fl >> 7; int k = fl & 127;
        *(float4*)&zs[b][k] = *(const float4*)&Z[(size_t)b * 4096 + kb + k];
    }
    __syncthreads();
    const float* Wp = W9 + (size_t)kb * 128 + t;
    float acc[32];
#pragma unroll
    for (int b = 0; b < 32; b++) acc[b] = 0.f;
    for (int k4 = 0; k4 < 32; k4++) {
        float w[4];
#pragma unroll
        for (int j = 0; j < 4; j++) w[j] = Wp[(k4 * 4 + j) * 128];
#pragma unroll
        for (int b = 0; b < 32; b++) {
            float4 z = *(const float4*)&zs[b][k4 * 4];
            acc[b] += z.x * w[0] + z.y * w[1] + z.z * w[2] + z.w * w[3];
        }
    }
    float* o = Mp + (size_t)kc * 32 * 128;
#pragma unroll
    for (int b = 0; b < 32; b++) o[b * 128 + t] = acc[b];
}

__global__ void k_red9(const float* __restrict__ Mp, float* __restrict__ Mu) {
    int idx = blockIdx.x * 256 + threadIdx.x;
    if (idx >= 4096) return;
    float a = 0.f;
    for (int p = 0; p < 32; p++) a += Mp[(size_t)p * 4096 + idx];
    Mu[idx] = a;
}

__global__ void k_bnfinal(const float* __restrict__ Mu, float* __restrict__ out) {
    int f = threadIdx.x;
    float v[32], s = 0.f;
#pragma unroll
    for (int b = 0; b < 32; b++) { v[b] = Mu[b * 128 + f]; s += v[b]; }
    float m = s * (1.f / 32.f), q = 0.f;
#pragma unroll
    for (int b = 0; b < 32; b++) { float d = v[b] - m; q += d * d; }
    float inv = rsqrtf(q * (1.f / 32.f) + EPSBN);
#pragma unroll
    for (int b = 0; b < 32; b++) out[b * 128 + f] = (v[b] - m) * inv;
}

// ---------------- host ----------------
extern "C" void kernel_launch(void* const* d_in, const int* in_sizes, int n_in,
                              void* d_out, int out_size, void* d_ws, size_t ws_size,
                              hipStream_t stream) {
    const float* x  = (const float*)d_in[0];
    const int* e0 = (const int*)d_in[1];
    const int* e1 = (const int*)d_in[2];
    const int* e2 = (const int*)d_in[3];
    const int* e3 = (const int*)d_in[4];
    const int* l0 = (const int*)d_in[5];
    const int* l1 = (const int*)d_in[6];
    const int* l2 = (const int*)d_in[7];
    const float* Wc1 = (const float*)d_in[8];
    const float* b1  = (const float*)d_in[9];
    const float* Wc2 = (const float*)d_in[10];
    const float* b2  = (const float*)d_in[11];
    const float* Wc3 = (const float*)d_in[12];
    const float* b3  = (const float*)d_in[13];
    const float* Wc4 = (const float*)d_in[14];
    const float* b4  = (const float*)d_in[15];
    const float* Wc5 = (const float*)d_in[16];
    const float* b5  = (const float*)d_in[17];
    const float* W6  = (const float*)d_in[18];
    const float* g6  = (const float*)d_in[20];
    const float* be6 = (const float*)d_in[21];
    const float* W7  = (const float*)d_in[22];
    const float* g7  = (const float*)d_in[24];
    const float* be7 = (const float*)d_in[25];
    const float* W8  = (const float*)d_in[26];
    const float* g8  = (const float*)d_in[28];
    const float* be8 = (const float*)d_in[29];
    const float* W9  = (const float*)d_in[30];
    float* out = (float*)d_out;

    char* p = (char*)d_ws;
    size_t o = 0;
    auto carve = [&](size_t bytes) {
        void* r = (void*)(p + o);
        o += (bytes + 255) & ~(size_t)255;
        return r;
    };
    float* xt  = (float*)carve((size_t)N0 * 96 * 4);       // 6.3 MB
    float* T1t = (float*)carve((size_t)N0 * 96 * 4);       // 6.3 MB
    float* Y1  = (float*)carve((size_t)N1 * 1024 * 4);     // 16.8 MB
    float* T1c = (float*)carve((size_t)N1 * 1024 * 4);     // 16.8 MB (reused all levels)
    float* Y2  = (float*)carve((size_t)N2 * 1024 * 4);     // 4.2 MB
    float* Y3  = (float*)carve((size_t)N3 * 1024 * 4);     // 0.5 MB
    float* Y4  = (float*)carve((size_t)N3 * 1024 * 4);     // 0.5 MB
    float* Hp  = (float*)carve((size_t)32 * BB * FDIM * 4);// 16.8 MB
    float* Zb0 = (float*)carve((size_t)BB * FDIM * 4);
    float* Zb1 = (float*)carve((size_t)BB * FDIM * 4);
    float* Mp  = (float*)carve((size_t)32 * BB * LDIM * 4);
    float* Mu  = (float*)carve((size_t)BB * LDIM * 4);
    int* deg  = (int*)carve(NT * sizeof(int));
    int* offs = (int*)carve((NT + 1) * sizeof(int));
    int* cur  = (int*)carve(NT * sizeof(int));
    int* ccol = (int*)carve(ET * sizeof(int));
    float* cw = (float*)carve(ET * sizeof(float));
    (void)ws_size;

    // CSR for all 4 levels
    hipMemsetAsync(deg, 0, NT * sizeof(int), stream);
    k_count<<<(ET + 255) / 256, 256, 0, stream>>>(e0, e1, e2, e3, deg);
    k_scan<<<1, 1024, 0, stream>>>(deg, offs, cur);
    k_scatter<<<(ET + 255) / 256, 256, 0, stream>>>(e0, e1, e2, e3, deg, cur, ccol, cw);

    const int* off0 = offs;
    const int* off1 = offs + N0;
    const int* off2 = offs + N0 + N1;
    const int* off3 = offs + N0 + N1 + N2;

    // node-major transpose of x
    k_transpose<<<N0 / 32, dim3(32, 8), 0, stream>>>(x, xt);

    // level 0
    k_prop0<<<(N0 * 96) / 256, 256, 0, stream>>>(xt, T1t, off0, ccol, cw);
    k_comb0<<<N1, 64, 0, stream>>>(xt, T1t, off0, ccol, cw, l0, Wc1, b1, Y1);
    // level 1
    k_propC<<<(N1 * 1024) / 256, 256, 0, stream>>>(Y1, T1c, off1, ccol, cw);
    k_combC<<<N2, 64, 0, stream>>>(Y1, T1c, off1, ccol, cw, l1, Wc2, b2, Y2, 1, 0);
    // level 2
    k_propC<<<(N2 * 1024) / 256, 256, 0, stream>>>(Y2, T1c, off2, ccol, cw);
    k_combC<<<N3, 64, 0, stream>>>(Y2, T1c, off2, ccol, cw, l2, Wc3, b3, Y3, 1, 0);
    // level 3
    k_propC<<<(N3 * 1024) / 256, 256, 0, stream>>>(Y3, T1c, off3, ccol, cw);
    k_combC<<<N3, 64, 0, stream>>>(Y3, T1c, off3, ccol, cw, nullptr, Wc4, b4, Y4, 1, 0);
    // level 4 -> batch-major Z
    k_propC<<<(N3 * 1024) / 256, 256, 0, stream>>>(Y4, T1c, off3, ccol, cw);
    k_combC<<<N3, 64, 0, stream>>>(Y4, T1c, off3, ccol, cw, nullptr, Wc5, b5, Zb0, 0, 1);

    // MLP
    const float* Ws[3]  = { W6, W7, W8 };
    const float* gs[3]  = { g6, g7, g8 };
    const float* bes[3] = { be6, be7, be8 };
    float* zin = Zb0; float* zout = Zb1;
    for (int l = 0; l < 3; l++) {
        k_gemm<<<dim3(16, 32), 256, 0, stream>>>(zin, Ws[l], Hp);
        k_bnrelu<<<64, 256, 0, stream>>>(Hp, gs[l], bes[l], zout);
        float* tmp = zin; zin = zout; zout = tmp;
    }
    k_gemm9<<<32, 128, 0, stream>>>(zin, W9, Mp);
    k_red9<<<16, 256, 0, stream>>>(Mp, Mu);
    k_bnfinal<<<1, 128, 0, stream>>>(Mu, out);
    (void)out_size; (void)n_in; (void)in_sizes;
}

// Round 6
// 532.088 us; speedup vs baseline: 2.0198x; 1.1496x over previous
//
#include <hip/hip_runtime.h>
#include <hip/hip_bf16.h>

// ---- problem constants (fixed by setup_inputs) ----
#define BB 32
#define HD 32
#define N0 16384
#define C0 3
#define E0v 131072
#define N1 4096
#define E1v 32768
#define N2 1024
#define E2v 8192
#define N3 128
#define E3v 1024
#define FDIM 4096
#define LDIM 128
#define NT (N0 + N1 + N2 + N3)     // 21632
#define ET (E0v + E1v + E2v + E3v) // 173056
#define EPSBN 1e-5f
#define KC 64                       // GEMM split-K chunks (K=4096/64)
// All tensors are float32 (established round 4).

// ---------------- CSR build (all 4 levels in one pass) ----------------
__global__ void k_count(const int* __restrict__ e0, const int* __restrict__ e1,
                        const int* __restrict__ e2, const int* __restrict__ e3,
                        int* __restrict__ deg) {
    int e = blockIdx.x * 256 + threadIdx.x;
    if (e >= ET) return;
    const int* p; int idx, nb;
    if (e < E0v)                     { p = e0; idx = e; nb = 0; }
    else if (e < E0v + E1v)          { p = e1; idx = e - E0v; nb = N0; }
    else if (e < E0v + E1v + E2v)    { p = e2; idx = e - E0v - E1v; nb = N0 + N1; }
    else                             { p = e3; idx = e - E0v - E1v - E2v; nb = N0 + N1 + N2; }
    atomicAdd(&deg[nb + p[idx]], 1);
}

__global__ void __launch_bounds__(1024) k_scan(const int* __restrict__ deg,
                                               int* __restrict__ offs, int* __restrict__ cur) {
    __shared__ int ss[1024];
    int t = threadIdx.x, base = t * 22;
    int loc[22]; int s = 0;
#pragma unroll
    for (int i = 0; i < 22; i++) {
        int idx = base + i;
        int v = (idx < NT) ? deg[idx] : 0;
        loc[i] = s; s += v;
    }
    ss[t] = s;
    __syncthreads();
    int run = s;
    for (int o = 1; o < 1024; o <<= 1) {
        int y = (t >= o) ? ss[t - o] : 0;
        __syncthreads();
        run += y; ss[t] = run;
        __syncthreads();
    }
    int excl = run - s;
#pragma unroll
    for (int i = 0; i < 22; i++) {
        int idx = base + i;
        if (idx < NT) { int v = excl + loc[i]; offs[idx] = v; cur[idx] = v; }
    }
    if (t == 0) offs[NT] = ET;
}

__global__ void k_scatter(const int* __restrict__ e0, const int* __restrict__ e1,
                          const int* __restrict__ e2, const int* __restrict__ e3,
                          const int* __restrict__ deg, int* __restrict__ cur,
                          int* __restrict__ ccol, float* __restrict__ cw) {
    int e = blockIdx.x * 256 + threadIdx.x;
    if (e >= ET) return;
    const int* p; int idx, nb, El;
    if (e < E0v)                  { p = e0; idx = e; nb = 0; El = E0v; }
    else if (e < E0v + E1v)       { p = e1; idx = e - E0v; nb = N0; El = E1v; }
    else if (e < E0v + E1v + E2v) { p = e2; idx = e - E0v - E1v; nb = N0 + N1; El = E2v; }
    else                          { p = e3; idx = e - E0v - E1v - E2v; nb = N0 + N1 + N2; El = E3v; }
    int r = p[idx], c = p[El + idx];
    int pos = atomicAdd(&cur[nb + r], 1);
    int dr = deg[nb + r], dc = deg[nb + c];
    float w = 0.f;
    if (dr > 0 && dc > 0)
        w = -(1.f / sqrtf((float)dr)) * (1.f / sqrtf((float)dc));
    ccol[pos] = c;  // level-local col index
    cw[pos] = w;
}

// ---------------- transpose x [B][N0][3] -> xt [N0][96] (q = b*3+c) ----------------
__global__ void k_transpose(const float* __restrict__ x, float* __restrict__ xt) {
    __shared__ float t0[32][33], t1[32][33], t2[32][33];
    int tx = threadIdx.x, ty = threadIdx.y;      // (32, 8)
    int n0 = blockIdx.x * 32;
#pragma unroll
    for (int i = 0; i < 4; i++) {
        int b = ty * 4 + i;
        size_t base = ((size_t)b * N0 + n0 + tx) * 3;
        t0[tx][b] = x[base];
        t1[tx][b] = x[base + 1];
        t2[tx][b] = x[base + 2];
    }
    __syncthreads();
#pragma unroll
    for (int i = 0; i < 4; i++) {
        int nl = ty * 4 + i;
        size_t o = (size_t)(n0 + nl) * 96 + tx * 3;
        xt[o]     = t0[nl][tx];
        xt[o + 1] = t1[nl][tx];
        xt[o + 2] = t2[nl][tx];
    }
}

// ---------------- level-0 prop ----------------
__global__ void k_prop0(const float* __restrict__ xt, float* __restrict__ T1t,
                        const int* __restrict__ offs, const int* __restrict__ ccol,
                        const float* __restrict__ cw) {
    int idx = blockIdx.x * 256 + threadIdx.x;  // total N0*96
    int n = (unsigned)idx / 96u;
    int q = idx - n * 96;
    int s = offs[n], e = offs[n + 1];
    float acc = 0.f;
    for (int k = s; k < e; k++)
        acc += cw[k] * xt[(size_t)ccol[k] * 96 + q];
    T1t[idx] = acc;
}

// ---------------- level-0 combine ----------------
__global__ void k_comb0(const float* __restrict__ xt, const float* __restrict__ T1t,
                        const int* __restrict__ offs, const int* __restrict__ ccol,
                        const float* __restrict__ cw, const int* __restrict__ pool,
                        const float* __restrict__ W, const float* __restrict__ bias,
                        float* __restrict__ Yout) {
    __shared__ float s0[96], s1[96], s2[96], sw[288], sb[32];
    int t = threadIdx.x;
    int j = blockIdx.x;
    int n = pool[j];
    size_t nb = (size_t)n * 96;
    s0[t] = xt[nb + t];
    s1[t] = T1t[nb + t];
    if (t < 32) { s0[64 + t] = xt[nb + 64 + t]; s1[64 + t] = T1t[nb + 64 + t]; }
    {
        int s = offs[n], e = offs[n + 1];
        float a0 = 0.f, a1 = 0.f;
        for (int k = s; k < e; k++) {
            const float* bp = T1t + (size_t)ccol[k] * 96;
            float w = cw[k];
            a0 += w * bp[t];
            if (t < 32) a1 += w * bp[64 + t];
        }
        s2[t] = a0;
        if (t < 32) s2[64 + t] = a1;
    }
    for (int i = t; i < 288; i += 64) sw[i] = W[i];
    if (t < 32) sb[t] = bias[t];
    __syncthreads();

    int f0 = (t & 7) * 4;
    int b0 = (t >> 3) * 4;
    float acc[4][4];
#pragma unroll
    for (int bi = 0; bi < 4; bi++)
#pragma unroll
        for (int fi = 0; fi < 4; fi++) acc[bi][fi] = sb[f0 + fi];
#pragma unroll
    for (int c = 0; c < 3; c++) {
        float4 w0 = *(float4*)&sw[(0 * 3 + c) * 32 + f0];
        float4 w1 = *(float4*)&sw[(1 * 3 + c) * 32 + f0];
        float4 w2 = *(float4*)&sw[(2 * 3 + c) * 32 + f0];
#pragma unroll
        for (int bi = 0; bi < 4; bi++) {
            int b = b0 + bi;
            float x0 = s0[b * 3 + c], x1 = s1[b * 3 + c];
            float x2 = 2.f * s2[b * 3 + c] - x0;
            acc[bi][0] += x0 * w0.x + x1 * w1.x + x2 * w2.x;
            acc[bi][1] += x0 * w0.y + x1 * w1.y + x2 * w2.y;
            acc[bi][2] += x0 * w0.z + x1 * w1.z + x2 * w2.z;
            acc[bi][3] += x0 * w0.w + x1 * w1.w + x2 * w2.w;
        }
    }
#pragma unroll
    for (int bi = 0; bi < 4; bi++) {
        float4 v = { acc[bi][0], acc[bi][1], acc[bi][2], acc[bi][3] };
        *(float4*)&Yout[(size_t)j * 1024 + (b0 + bi) * 32 + f0] = v;
    }
}

// ---------------- levels 1-4 prop ----------------
__global__ void k_propC(const float* __restrict__ Yin, float* __restrict__ T1,
                        const int* __restrict__ offs, const int* __restrict__ ccol,
                        const float* __restrict__ cw) {
    int idx = blockIdx.x * 256 + threadIdx.x;
    int n = idx >> 10;
    int q = idx & 1023;
    int s = offs[n], e = offs[n + 1];
    float acc = 0.f;
    for (int k = s; k < e; k++)
        acc += cw[k] * Yin[((size_t)ccol[k] << 10) + q];
    T1[idx] = acc;
}

// ---------------- levels 1-4 combine ----------------
__global__ void k_combC(const float* __restrict__ Yin, const float* __restrict__ T1,
                        const int* __restrict__ offs, const int* __restrict__ ccol,
                        const float* __restrict__ cw, const int* __restrict__ pool,
                        const float* __restrict__ W, const float* __restrict__ bias,
                        float* __restrict__ Yout, int doTanh, int bMajor) {
    __shared__ float s0[32 * 33], s1[32 * 33], s2[32 * 33], sw[3072], sb[32];
    int t = threadIdx.x;
    int j = blockIdx.x;
    int n = pool ? pool[j] : j;
    size_t nb = (size_t)n << 10;
#pragma unroll
    for (int i = 0; i < 16; i++) {
        int q = t + i * 64;
        int li = (q >> 5) * 33 + (q & 31);
        s0[li] = Yin[nb + q];
        s1[li] = T1[nb + q];
    }
    {
        int s = offs[n], e = offs[n + 1];
        float ga[16];
#pragma unroll
        for (int i = 0; i < 16; i++) ga[i] = 0.f;
        for (int k = s; k < e; k++) {
            const float* bp = T1 + ((size_t)ccol[k] << 10);
            float w = cw[k];
#pragma unroll
            for (int i = 0; i < 16; i++) ga[i] += w * bp[t + i * 64];
        }
#pragma unroll
        for (int i = 0; i < 16; i++) {
            int q = t + i * 64;
            s2[(q >> 5) * 33 + (q & 31)] = ga[i];
        }
    }
    for (int i = t; i < 768; i += 64) ((float4*)sw)[i] = ((const float4*)W)[i];
    if (t < 32) sb[t] = bias[t];
    __syncthreads();

    int f0 = (t & 7) * 4;
    int b0 = (t >> 3) * 4;
    float acc[4][4];
#pragma unroll
    for (int bi = 0; bi < 4; bi++)
#pragma unroll
        for (int fi = 0; fi < 4; fi++) acc[bi][fi] = sb[f0 + fi];
    for (int c = 0; c < 32; c++) {
        float4 w0 = *(float4*)&sw[c * 32 + f0];
        float4 w1 = *(float4*)&sw[1024 + c * 32 + f0];
        float4 w2 = *(float4*)&sw[2048 + c * 32 + f0];
#pragma unroll
        for (int bi = 0; bi < 4; bi++) {
            int li = (b0 + bi) * 33 + c;
            float x0 = s0[li], x1 = s1[li];
            float x2 = 2.f * s2[li] - x0;
            acc[bi][0] += x0 * w0.x + x1 * w1.x + x2 * w2.x;
            acc[bi][1] += x0 * w0.y + x1 * w1.y + x2 * w2.y;
            acc[bi][2] += x0 * w0.z + x1 * w1.z + x2 * w2.z;
            acc[bi][3] += x0 * w0.w + x1 * w1.w + x2 * w2.w;
        }
    }
    if (doTanh) {
#pragma unroll
        for (int bi = 0; bi < 4; bi++)
#pragma unroll
            for (int fi = 0; fi < 4; fi++) acc[bi][fi] = tanhf(acc[bi][fi]);
    }
#pragma unroll
    for (int bi = 0; bi < 4; bi++) {
        float4 v = { acc[bi][0], acc[bi][1], acc[bi][2], acc[bi][3] };
        if (bMajor)
            *(float4*)&Yout[(size_t)(b0 + bi) * FDIM + j * 32 + f0] = v;
        else
            *(float4*)&Yout[((size_t)j << 10) + (b0 + bi) * 32 + f0] = v;
    }
}

// ---------------- MLP ----------------
// Z[32][4096] @ W[4096][4096] -> Hp[kc][32][4096] partials.
// grid (16, KC), block 256 = 64 f-threads (4f each) x 4 b-groups (8b each).
// Per 4 k: 4 float4 W loads + 8 ds_read_b128 + 128 FMA.
__global__ void __launch_bounds__(256, 2) k_gemm(const float* __restrict__ Z,
                                                 const float* __restrict__ W,
                                                 float* __restrict__ Hp) {
    int t = threadIdx.x; int bx = blockIdx.x; int kc = blockIdx.y; int kb = kc * 64;
    __shared__ float zs[32][64];
    for (int i = t; i < 512; i += 256) {
        int fl = i * 4; int b = fl >> 6; int k = fl & 63;
        *(float4*)&zs[b][k] = *(const float4*)&Z[(size_t)b * 4096 + kb + k];
    }
    __syncthreads();
    int ft = t & 63, bt = t >> 6;
    int f0 = bx * 256 + ft * 4;
    int b0 = bt * 8;
    const float* Wp = W + (size_t)kb * 4096 + f0;
    float acc[8][4];
#pragma unroll
    for (int bi = 0; bi < 8; bi++)
#pragma unroll
        for (int fi = 0; fi < 4; fi++) acc[bi][fi] = 0.f;
    for (int k4 = 0; k4 < 16; k4++) {
        float4 w[4];
#pragma unroll
        for (int j = 0; j < 4; j++)
            w[j] = *(const float4*)&Wp[(size_t)(k4 * 4 + j) * 4096];
        float4 z[8];
#pragma unroll
        for (int bi = 0; bi < 8; bi++)
            z[bi] = *(const float4*)&zs[b0 + bi][k4 * 4];
#pragma unroll
        for (int bi = 0; bi < 8; bi++) {
            acc[bi][0] += z[bi].x * w[0].x + z[bi].y * w[1].x + z[bi].z * w[2].x + z[bi].w * w[3].x;
            acc[bi][1] += z[bi].x * w[0].y + z[bi].y * w[1].y + z[bi].z * w[2].y + z[bi].w * w[3].y;
            acc[bi][2] += z[bi].x * w[0].z + z[bi].y * w[1].z + z[bi].z * w[2].z + z[bi].w * w[3].z;
            acc[bi][3] += z[bi].x * w[0].w + z[bi].y * w[1].w + z[bi].z * w[2].w + z[bi].w * w[3].w;
        }
    }
    float* o = Hp + (size_t)kc * 32 * 4096;
#pragma unroll
    for (int bi = 0; bi < 8; bi++) {
        float4 v = { acc[bi][0], acc[bi][1], acc[bi][2], acc[bi][3] };
        *(float4*)&o[(size_t)(b0 + bi) * 4096 + f0] = v;
    }
}

// reduce KC partials + BN(batch) + affine + relu. grid 128, block 256 = 32f x 8bq(4b).
__global__ void k_bnrelu(const float* __restrict__ Hp, const float* __restrict__ g,
                         const float* __restrict__ be, float* __restrict__ Zo) {
    __shared__ float sA[8][33], sB[8][33], sm[32], si[32];
    int t = threadIdx.x; int fq = t & 31; int bq = t >> 5;
    int f = blockIdx.x * 32 + fq;
    float v[4];
#pragma unroll
    for (int i = 0; i < 4; i++) v[i] = 0.f;
    for (int p = 0; p < KC; p++) {
        const float* hp = Hp + (size_t)p * 32 * 4096;
#pragma unroll
        for (int i = 0; i < 4; i++) v[i] += hp[(size_t)(bq * 4 + i) * 4096 + f];
    }
    float a = 0.f, q = 0.f;
#pragma unroll
    for (int i = 0; i < 4; i++) { a += v[i]; q += v[i] * v[i]; }
    sA[bq][fq] = a; sB[bq][fq] = q;
    __syncthreads();
    if (t < 32) {
        float m = 0.f, qq = 0.f;
#pragma unroll
        for (int i = 0; i < 8; i++) { m += sA[i][t]; qq += sB[i][t]; }
        m *= (1.f / 32.f);
        qq = qq * (1.f / 32.f) - m * m;
        sm[t] = m; si[t] = rsqrtf(fmaxf(qq, 0.f) + EPSBN);
    }
    __syncthreads();
    float m = sm[fq], inv = si[fq], gg = g[f], bb = be[f];
#pragma unroll
    for (int i = 0; i < 4; i++) {
        float o = (v[i] - m) * inv * gg + bb;
        Zo[(size_t)(bq * 4 + i) * 4096 + f] = fmaxf(o, 0.f);
    }
}

// Z[32][4096] @ W9[4096][128] -> Mp[kc][32][128]. grid KC, block 128 = 32f(4) x 4bq(8).
__global__ void __launch_bounds__(128, 2) k_gemm9(const float* __restrict__ Z,
                                                  const float* __restrict__ W9,
                                                  float* __restrict__ Mp) {
    int t = threadIdx.x; int kc = blockIdx.x; int kb = kc * 64;
    __shared__ float zs[32][64];
    for (int i = t; i < 512; i += 128) {
        int fl = i * 4; int b = fl >> 6; int k = fl & 63;
        *(float4*)&zs[b][k] = *(const float4*)&Z[(size_t)b * 4096 + kb + k];
    }
    __syncthreads();
    int ft = t & 31, bt = t >> 5;
    int f0 = ft * 4;
    int b0 = bt * 8;
    const float* Wp = W9 + (size_t)kb * 128 + f0;
    float acc[8][4];
#pragma unroll
    for (int bi = 0; bi < 8; bi++)
#pragma unroll
        for (int fi = 0; fi < 4; fi++) acc[bi][fi] = 0.f;
    for (int k4 = 0; k4 < 16; k4++) {
        float4 w[4];
#pragma unroll
        for (int j = 0; j < 4; j++)
            w[j] = *(const float4*)&Wp[(size_t)(k4 * 4 + j) * 128];
        float4 z[8];
#pragma unroll
        for (int bi = 0; bi < 8; bi++)
            z[bi] = *(const float4*)&zs[b0 + bi][k4 * 4];
#pragma unroll
        for (int bi = 0; bi < 8; bi++) {
            acc[bi][0] += z[bi].x * w[0].x + z[bi].y * w[1].x + z[bi].z * w[2].x + z[bi].w * w[3].x;
            acc[bi][1] += z[bi].x * w[0].y + z[bi].y * w[1].y + z[bi].z * w[2].y + z[bi].w * w[3].y;
            acc[bi][2] += z[bi].x * w[0].z + z[bi].y * w[1].z + z[bi].z * w[2].z + z[bi].w * w[3].z;
            acc[bi][3] += z[bi].x * w[0].w + z[bi].y * w[1].w + z[bi].z * w[2].w + z[bi].w * w[3].w;
        }
    }
    float* o = Mp + (size_t)kc * 32 * 128;
#pragma unroll
    for (int bi = 0; bi < 8; bi++) {
        float4 v = { acc[bi][0], acc[bi][1], acc[bi][2], acc[bi][3] };
        *(float4*)&o[(b0 + bi) * 128 + f0] = v;
    }
}

__global__ void k_red9(const float* __restrict__ Mp, float* __restrict__ Mu) {
    int idx = blockIdx.x * 256 + threadIdx.x;
    if (idx >= 4096) return;
    float a = 0.f;
    for (int p = 0; p < KC; p++) a += Mp[(size_t)p * 4096 + idx];
    Mu[idx] = a;
}

__global__ void k_bnfinal(const float* __restrict__ Mu, float* __restrict__ out) {
    int f = threadIdx.x;
    float v[32], s = 0.f;
#pragma unroll
    for (int b = 0; b < 32; b++) { v[b] = Mu[b * 128 + f]; s += v[b]; }
    float m = s * (1.f / 32.f), q = 0.f;
#pragma unroll
    for (int b = 0; b < 32; b++) { float d = v[b] - m; q += d * d; }
    float inv = rsqrtf(q * (1.f / 32.f) + EPSBN);
#pragma unroll
    for (int b = 0; b < 32; b++) out[b * 128 + f] = (v[b] - m) * inv;
}

// ---------------- host ----------------
extern "C" void kernel_launch(void* const* d_in, const int* in_sizes, int n_in,
                              void* d_out, int out_size, void* d_ws, size_t ws_size,
                              hipStream_t stream) {
    const float* x  = (const float*)d_in[0];
    const int* e0 = (const int*)d_in[1];
    const int* e1 = (const int*)d_in[2];
    const int* e2 = (const int*)d_in[3];
    const int* e3 = (const int*)d_in[4];
    const int* l0 = (const int*)d_in[5];
    const int* l1 = (const int*)d_in[6];
    const int* l2 = (const int*)d_in[7];
    const float* Wc1 = (const float*)d_in[8];
    const float* b1  = (const float*)d_in[9];
    const float* Wc2 = (const float*)d_in[10];
    const float* b2  = (const float*)d_in[11];
    const float* Wc3 = (const float*)d_in[12];
    const float* b3  = (const float*)d_in[13];
    const float* Wc4 = (const float*)d_in[14];
    const float* b4  = (const float*)d_in[15];
    const float* Wc5 = (const float*)d_in[16];
    const float* b5  = (const float*)d_in[17];
    const float* W6  = (const float*)d_in[18];
    const float* g6  = (const float*)d_in[20];
    const float* be6 = (const float*)d_in[21];
    const float* W7  = (const float*)d_in[22];
    const float* g7  = (const float*)d_in[24];
    const float* be7 = (const float*)d_in[25];
    const float* W8  = (const float*)d_in[26];
    const float* g8  = (const float*)d_in[28];
    const float* be8 = (const float*)d_in[29];
    const float* W9  = (const float*)d_in[30];
    float* out = (float*)d_out;

    char* p = (char*)d_ws;
    size_t o = 0;
    auto carve = [&](size_t bytes) {
        void* r = (void*)(p + o);
        o += (bytes + 255) & ~(size_t)255;
        return r;
    };
    // graph-phase buffers (dead by MLP time; Hp aliases this span)
    float* xt  = (float*)carve((size_t)N0 * 96 * 4);       // 6.3 MB
    float* T1t = (float*)carve((size_t)N0 * 96 * 4);       // 6.3 MB
    float* Y1  = (float*)carve((size_t)N1 * 1024 * 4);     // 16.8 MB
    float* T1c = (float*)carve((size_t)N1 * 1024 * 4);     // 16.8 MB (reused all levels)
    float* Y2  = (float*)carve((size_t)N2 * 1024 * 4);     // 4.2 MB
    float* Y3  = (float*)carve((size_t)N3 * 1024 * 4);     // 0.5 MB
    float* Y4  = (float*)carve((size_t)N3 * 1024 * 4);     // 0.5 MB
    float* Zb0 = (float*)carve((size_t)BB * FDIM * 4);
    float* Zb1 = (float*)carve((size_t)BB * FDIM * 4);
    float* Mp  = (float*)carve((size_t)KC * BB * LDIM * 4);
    float* Mu  = (float*)carve((size_t)BB * LDIM * 4);
    int* deg  = (int*)carve(NT * sizeof(int));
    int* offs = (int*)carve((NT + 1) * sizeof(int));
    int* cur  = (int*)carve(NT * sizeof(int));
    int* ccol = (int*)carve(ET * sizeof(int));
    float* cw = (float*)carve(ET * sizeof(float));
    float* Hp = xt;  // alias: KC*32*4096*4 = 33.6 MB fits in xt..T1c span (46.2 MB)
    (void)ws_size;

    // CSR for all 4 levels
    hipMemsetAsync(deg, 0, NT * sizeof(int), stream);
    k_count<<<(ET + 255) / 256, 256, 0, stream>>>(e0, e1, e2, e3, deg);
    k_scan<<<1, 1024, 0, stream>>>(deg, offs, cur);
    k_scatter<<<(ET + 255) / 256, 256, 0, stream>>>(e0, e1, e2, e3, deg, cur, ccol, cw);

    const int* off0 = offs;
    const int* off1 = offs + N0;
    const int* off2 = offs + N0 + N1;
    const int* off3 = offs + N0 + N1 + N2;

    // node-major transpose of x
    k_transpose<<<N0 / 32, dim3(32, 8), 0, stream>>>(x, xt);

    // level 0
    k_prop0<<<(N0 * 96) / 256, 256, 0, stream>>>(xt, T1t, off0, ccol, cw);
    k_comb0<<<N1, 64, 0, stream>>>(xt, T1t, off0, ccol, cw, l0, Wc1, b1, Y1);
    // level 1
    k_propC<<<(N1 * 1024) / 256, 256, 0, stream>>>(Y1, T1c, off1, ccol, cw);
    k_combC<<<N2, 64, 0, stream>>>(Y1, T1c, off1, ccol, cw, l1, Wc2, b2, Y2, 1, 0);
    // level 2
    k_propC<<<(N2 * 1024) / 256, 256, 0, stream>>>(Y2, T1c, off2, ccol, cw);
    k_combC<<<N3, 64, 0, stream>>>(Y2, T1c, off2, ccol, cw, l2, Wc3, b3, Y3, 1, 0);
    // level 3
    k_propC<<<(N3 * 1024) / 256, 256, 0, stream>>>(Y3, T1c, off3, ccol, cw);
    k_combC<<<N3, 64, 0, stream>>>(Y3, T1c, off3, ccol, cw, nullptr, Wc4, b4, Y4, 1, 0);
    // level 4 -> batch-major Z
    k_propC<<<(N3 * 1024) / 256, 256, 0, stream>>>(Y4, T1c, off3, ccol, cw);
    k_combC<<<N3, 64, 0, stream>>>(Y4, T1c, off3, ccol, cw, nullptr, Wc5, b5, Zb0, 0, 1);

    // MLP (Hp aliases graph buffers — graph section fully precedes this)
    const float* Ws[3]  = { W6, W7, W8 };
    const float* gs[3]  = { g6, g7, g8 };
    const float* bes[3] = { be6, be7, be8 };
    float* zin = Zb0; float* zout = Zb1;
    for (int l = 0; l < 3; l++) {
        k_gemm<<<dim3(16, KC), 256, 0, stream>>>(zin, Ws[l], Hp);
        k_bnrelu<<<128, 256, 0, stream>>>(Hp, gs[l], bes[l], zout);
        float* tmp = zin; zin = zout; zout = tmp;
    }
    k_gemm9<<<KC, 128, 0, stream>>>(zin, W9, Mp);
    k_red9<<<16, 256, 0, stream>>>(Mp, Mu);
    k_bnfinal<<<1, 128, 0, stream>>>(Mu, out);
    (void)out_size; (void)n_in; (void)in_sizes;
}